// Round 12
// baseline (240.391 us; speedup 1.0000x reference)
//
#include <hip/hip_runtime.h>
#include <hip/hip_fp16.h>
#include <math.h>

#define NN 50000
#define EE 800000
#define NB 196  // ceil(NN/256)
// IN_DIM = 128, HEADS*HIDDEN = 128, NUM_CLASSES = 10

typedef _Float16 f16x8 __attribute__((ext_vector_type(8)));
typedef float f32x4 __attribute__((ext_vector_type(4)));

__device__ inline float elu1(float x) { return x > 0.f ? x : expm1f(x); }

// ---------- prep: W1 transpose (f16) + W2 pack (f16, zero-padded) in one kernel ----------
__global__ __launch_bounds__(256) void build_weights(
    const float* __restrict__ Wq, const float* __restrict__ Wk,
    const float* __restrict__ Wv, const float* __restrict__ Ws,
    const float* __restrict__ Wq2, const float* __restrict__ bq2,
    const float* __restrict__ Wk2, const float* __restrict__ bk2,
    const float* __restrict__ Wv2, const float* __restrict__ bv2,
    const float* __restrict__ Ws2, const float* __restrict__ bs2,
    __half* __restrict__ Wt, __half* __restrict__ W2t, float* __restrict__ bias2)
{
    // part A (blocks 0..31): W2[128][10] x4 -> W2t[64][128] zero-padded + bias2[64]
    const int idx = blockIdx.x * 256 + threadIdx.x;
    if (idx < 8192) {
        const int col = idx >> 7, k = idx & 127;
        const int m = col >> 4, j = col & 15;
        const float* W = m == 0 ? Wq2 : m == 1 ? Wk2 : m == 2 ? Wv2 : Ws2;
        W2t[idx] = (__half)(j < 10 ? W[k * 10 + j] : 0.f);
    }
    if (idx < 64) {
        const int m = idx >> 4, j = idx & 15;
        const float* b = m == 0 ? bq2 : m == 1 ? bk2 : m == 2 ? bv2 : bs2;
        bias2[idx] = j < 10 ? b[j] : 0.f;
    }
    // part B (all 64 blocks): W1[k][c] -> Wt[mat][c][k] f16 via LDS tile transpose
    __shared__ float tile[32][33];
    const int mat = blockIdx.x >> 4;
    const int tid = blockIdx.x & 15;
    const int k0 = (tid >> 2) * 32, c0 = (tid & 3) * 32;
    const float* W = mat == 0 ? Wq : mat == 1 ? Wk : mat == 2 ? Wv : Ws;
    const int r = threadIdx.x >> 5;   // 0..7
    const int c = threadIdx.x & 31;
    for (int rr = r; rr < 32; rr += 8) tile[rr][c] = W[(size_t)(k0 + rr) * 128 + c0 + c];
    __syncthreads();
    for (int rr = r; rr < 32; rr += 8)
        Wt[((size_t)mat * 128 + c0 + rr) * 128 + k0 + c] = (__half)tile[c][rr];
}

// ---------- CSR build: histogram, multi-block scan, scatter ----------
__global__ __launch_bounds__(256) void deg_count(
    const int* __restrict__ dst, int* __restrict__ deg)
{
    const int e = blockIdx.x * 256 + threadIdx.x;
    if (e >= EE) return;
    atomicAdd(&deg[dst[e]], 1);
}

__global__ __launch_bounds__(256) void block_sums(
    const int* __restrict__ deg, int* __restrict__ bsum)
{
    __shared__ int ws[4];
    const int t = threadIdx.x;
    const int idx = blockIdx.x * 256 + t;
    int d = (idx < NN) ? deg[idx] : 0;
    #pragma unroll
    for (int off = 32; off; off >>= 1) d += __shfl_down(d, off, 64);
    if ((t & 63) == 0) ws[t >> 6] = d;
    __syncthreads();
    if (t == 0) bsum[blockIdx.x] = ws[0] + ws[1] + ws[2] + ws[3];
}

__global__ __launch_bounds__(256) void scan_bsums(int* __restrict__ bsum)
{
    __shared__ int s[256];
    const int t = threadIdx.x;
    int v = (t < NB) ? bsum[t] : 0;
    s[t] = v;
    __syncthreads();
    for (int off = 1; off < 256; off <<= 1) {
        int u = (t >= off) ? s[t - off] : 0;
        __syncthreads();
        s[t] += u;
        __syncthreads();
    }
    if (t < NB) bsum[t] = (t == 0) ? 0 : s[t - 1];
}

__global__ __launch_bounds__(256) void write_rowptr(
    const int* __restrict__ deg, const int* __restrict__ bsum,
    int* __restrict__ rowptr, int* __restrict__ cursor)
{
    __shared__ int s[256];
    const int t = threadIdx.x;
    const int idx = blockIdx.x * 256 + t;
    const int d = (idx < NN) ? deg[idx] : 0;
    s[t] = d;
    __syncthreads();
    for (int off = 1; off < 256; off <<= 1) {
        int u = (t >= off) ? s[t - off] : 0;
        __syncthreads();
        s[t] += u;
        __syncthreads();
    }
    const int excl = ((t == 0) ? 0 : s[t - 1]) + bsum[blockIdx.x];
    if (idx < NN) {
        rowptr[idx] = excl;
        cursor[idx] = excl;
    }
    if (idx == NN - 1) rowptr[NN] = excl + d;  // == EE
}

__global__ __launch_bounds__(256) void scatter_edges(
    const int* __restrict__ src, const int* __restrict__ dst,
    int* __restrict__ cursor, int* __restrict__ esrc)
{
    const int e = blockIdx.x * 256 + threadIdx.x;
    if (e >= EE) return;
    const int d = dst[e];
    const int pos = atomicAdd(&cursor[d], 1);
    esrc[pos] = src[e];
}

// ---------- layer-1 projections via MFMA: 2 matrices per block (blockIdx.y) ----------
// Reads x in f32 directly (no convert kernel), converts to f16 fragments in-register.
// All outputs f16 (q, k, v, skip). 1564 waves for store-latency hiding.
__global__ __launch_bounds__(128) void gemm_l1_mfma(
    const float* __restrict__ x, const __half* __restrict__ Wt,
    const float* __restrict__ bq, const float* __restrict__ bk,
    const float* __restrict__ bv, const float* __restrict__ bs,
    __half* __restrict__ oqh, __half* __restrict__ okh,
    __half* __restrict__ ovh, __half* __restrict__ osh)
{
    const int pair = blockIdx.y;  // 0: mats {0,1}; 1: mats {2,3}
    const int t = threadIdx.x;
    const int wave = t >> 6;
    const int lane = t & 63;
    const int l = lane & 15;
    const int g = lane >> 4;  // 0..3
    const int wrow0 = blockIdx.x * 128 + wave * 64;
    if (wrow0 >= NN) return;
    const bool full = (wrow0 + 64 <= NN);

    // x fragments (B operand): f32 load + in-register cvt; lane&15 = row-in-tile
    f16x8 xf[4][4];
    #pragma unroll
    for (int rt = 0; rt < 4; ++rt) {
        int arow = wrow0 + rt * 16 + l;
        if (!full && arow >= NN) arow = NN - 1;  // clamp: garbage rows never stored
        #pragma unroll
        for (int kk = 0; kk < 4; ++kk) {
            const float* xp = x + (size_t)arow * 128 + kk * 32 + g * 8;
            const float4 a = *(const float4*)xp;
            const float4 b = *(const float4*)(xp + 4);
            f16x8 f;
            f[0] = (_Float16)a.x; f[1] = (_Float16)a.y;
            f[2] = (_Float16)a.z; f[3] = (_Float16)a.w;
            f[4] = (_Float16)b.x; f[5] = (_Float16)b.y;
            f[6] = (_Float16)b.z; f[7] = (_Float16)b.w;
            xf[rt][kk] = f;
        }
    }

    for (int mi = 0; mi < 2; ++mi) {
        const int mat = pair * 2 + mi;
        const float* b = mat == 0 ? bq : mat == 1 ? bk : mat == 2 ? bv : bs;
        const _Float16* wt = (const _Float16*)Wt + (size_t)mat * 128 * 128;

        f16x8 wf[4], wfn[4];
        #pragma unroll
        for (int kk = 0; kk < 4; ++kk)
            wf[kk] = *(const f16x8*)(wt + (size_t)l * 128 + kk * 32 + g * 8);

        for (int ct = 0; ct < 8; ++ct) {
            if (ct < 7) {
                const int ncol = (ct + 1) * 16 + l;
                #pragma unroll
                for (int kk = 0; kk < 4; ++kk)
                    wfn[kk] = *(const f16x8*)(wt + (size_t)ncol * 128 + kk * 32 + g * 8);
            }
            f32x4 acc[4];
            #pragma unroll
            for (int rt = 0; rt < 4; ++rt) acc[rt] = (f32x4){0.f, 0.f, 0.f, 0.f};
            #pragma unroll
            for (int kk = 0; kk < 4; ++kk)
                #pragma unroll
                for (int rt = 0; rt < 4; ++rt)
                    acc[rt] = __builtin_amdgcn_mfma_f32_16x16x32_f16(wf[kk], xf[rt][kk], acc[rt], 0, 0, 0);

            const int col0 = ct * 16 + g * 4;
            const float4 bias = *(const float4*)(b + col0);
            __half* o = mat == 0 ? oqh : mat == 1 ? okh : mat == 2 ? ovh : osh;
            #pragma unroll
            for (int rt = 0; rt < 4; ++rt) {
                const int row = wrow0 + rt * 16 + l;
                if (full || row < NN) {
                    __half* p = o + (size_t)row * 128 + col0;
                    *(__half2*)p = __floats2half2_rn(acc[rt][0] + bias.x, acc[rt][1] + bias.y);
                    *(__half2*)(p + 2) = __floats2half2_rn(acc[rt][2] + bias.z, acc[rt][3] + bias.w);
                }
            }
            #pragma unroll
            for (int kk = 0; kk < 4; ++kk) wf[kk] = wfn[kk];
        }
    }
}

// ---------- layer-1 fused attention + skip + ELU -> h (fp16) ----------
// static-shift softmax (shift-invariant; logits ~ N(0,1) so exp(lg-4) is safe).
__global__ __launch_bounds__(256) void node_attn1(
    const __half* __restrict__ q1, const __half* __restrict__ k1,
    const __half* __restrict__ v1,
    const int* __restrict__ rowptr, const int* __restrict__ esrc,
    const __half* __restrict__ skiph,  // x @ Ws + bs (f16)
    __half* __restrict__ hb)           // out: h = elu(skip + attn), fp16
{
    const int t = threadIdx.x;
    const int wid = __builtin_amdgcn_readfirstlane(t >> 6);
    const int d = blockIdx.x * 4 + wid;
    if (d >= NN) return;
    const int lane = t & 63;
    const int ch2 = lane << 1;

    const int beg = rowptr[d];
    const int end = rowptr[d + 1];

    float2 qv = __half22float2(*(const __half2*)(q1 + (size_t)d * 128 + ch2));
    qv.x *= 0.17677669529663687f;  // fold 1/sqrt(32) into q
    qv.y *= 0.17677669529663687f;

    float2 accA = make_float2(0.f, 0.f), accB = make_float2(0.f, 0.f);
    float sA = 0.f, sB = 0.f;

    int i = beg;
    int sa = (i < end) ? esrc[i] : 0;
    int sb = (i + 1 < end) ? esrc[i + 1] : 0;
    __half2 kA = *(const __half2*)(k1 + (size_t)sa * 128 + ch2);
    __half2 vA = *(const __half2*)(v1 + (size_t)sa * 128 + ch2);
    __half2 kB = *(const __half2*)(k1 + (size_t)sb * 128 + ch2);
    __half2 vB = *(const __half2*)(v1 + (size_t)sb * 128 + ch2);

    while (i + 1 < end) {
        const int ni = i + 2;
        const int nsa = (ni < end) ? esrc[ni] : 0;
        const int nsb = (ni + 1 < end) ? esrc[ni + 1] : 0;
        const __half2 nkA = *(const __half2*)(k1 + (size_t)nsa * 128 + ch2);
        const __half2 nvA = *(const __half2*)(v1 + (size_t)nsa * 128 + ch2);
        const __half2 nkB = *(const __half2*)(k1 + (size_t)nsb * 128 + ch2);
        const __half2 nvB = *(const __half2*)(v1 + (size_t)nsb * 128 + ch2);

        const float2 kAf = __half22float2(kA);
        const float2 kBf = __half22float2(kB);
        const float2 vAf = __half22float2(vA);
        const float2 vBf = __half22float2(vB);

        float pA = qv.x * kAf.x + qv.y * kAf.y;
        float pB = qv.x * kBf.x + qv.y * kBf.y;
        pA += __shfl_xor(pA, 8, 16); pB += __shfl_xor(pB, 8, 16);
        pA += __shfl_xor(pA, 4, 16); pB += __shfl_xor(pB, 4, 16);
        pA += __shfl_xor(pA, 2, 16); pB += __shfl_xor(pB, 2, 16);
        pA += __shfl_xor(pA, 1, 16); pB += __shfl_xor(pB, 1, 16);

        const float exA = __expf(pA - 4.0f);
        accA.x += exA * vAf.x;
        accA.y += exA * vAf.y;
        sA += exA;

        const float exB = __expf(pB - 4.0f);
        accB.x += exB * vBf.x;
        accB.y += exB * vBf.y;
        sB += exB;

        kA = nkA; vA = nvA; kB = nkB; vB = nvB;
        i = ni;
    }
    if (i < end) {  // odd tail -> chain A
        const float2 kAf = __half22float2(kA);
        const float2 vAf = __half22float2(vA);
        float pA = qv.x * kAf.x + qv.y * kAf.y;
        pA += __shfl_xor(pA, 8, 16);
        pA += __shfl_xor(pA, 4, 16);
        pA += __shfl_xor(pA, 2, 16);
        pA += __shfl_xor(pA, 1, 16);
        const float exA = __expf(pA - 4.0f);
        accA.x += exA * vAf.x;
        accA.y += exA * vAf.y;
        sA += exA;
    }

    const float inv = 1.f / (sA + sB + 1e-16f);
    float2 o = __half22float2(*(const __half2*)(skiph + (size_t)d * 128 + ch2));
    o.x = elu1(o.x + (accA.x + accB.x) * inv);
    o.y = elu1(o.y + (accA.y + accB.y) * inv);
    *(__half2*)(hb + (size_t)d * 128 + ch2) = __floats2half2_rn(o.x, o.y);
}

// ---------- layer-2 projections via MFMA: h[N,128] @ W2t^T + bias2 ----------
// ct tile = matrix: 0->q2h[N][16], 1->k half of kv2h, 2->v half, 3->s2 (f32 out).
__global__ __launch_bounds__(128) void node_l2_mfma(
    const __half* __restrict__ hb, const __half* __restrict__ W2t,
    const float* __restrict__ bias2,
    __half* __restrict__ q2h, __half* __restrict__ kv2h,
    float* __restrict__ out)
{
    const int t = threadIdx.x;
    const int wave = t >> 6;
    const int lane = t & 63;
    const int l = lane & 15;
    const int g = lane >> 4;  // 0..3
    const int wrow0 = blockIdx.x * 128 + wave * 64;
    if (wrow0 >= NN) return;
    const bool full = (wrow0 + 64 <= NN);

    f16x8 hf[4][4];
    #pragma unroll
    for (int rt = 0; rt < 4; ++rt) {
        int arow = wrow0 + rt * 16 + l;
        if (!full && arow >= NN) arow = NN - 1;
        #pragma unroll
        for (int kk = 0; kk < 4; ++kk)
            hf[rt][kk] = *(const f16x8*)((const _Float16*)hb + (size_t)arow * 128 + kk * 32 + g * 8);
    }

    #pragma unroll
    for (int ct = 0; ct < 4; ++ct) {
        const int col = ct * 16 + l;
        f16x8 wf[4];
        #pragma unroll
        for (int kk = 0; kk < 4; ++kk)
            wf[kk] = *(const f16x8*)((const _Float16*)W2t + (size_t)col * 128 + kk * 32 + g * 8);

        f32x4 acc[4];
        #pragma unroll
        for (int rt = 0; rt < 4; ++rt) acc[rt] = (f32x4){0.f, 0.f, 0.f, 0.f};
        #pragma unroll
        for (int kk = 0; kk < 4; ++kk)
            #pragma unroll
            for (int rt = 0; rt < 4; ++rt)
                acc[rt] = __builtin_amdgcn_mfma_f32_16x16x32_f16(wf[kk], hf[rt][kk], acc[rt], 0, 0, 0);

        const int c0 = g * 4;  // within-tile column base
        const float4 bias = *(const float4*)(bias2 + ct * 16 + c0);
        #pragma unroll
        for (int rt = 0; rt < 4; ++rt) {
            const int row = wrow0 + rt * 16 + l;
            if (full || row < NN) {
                float4 r;
                r.x = acc[rt][0] + bias.x;
                r.y = acc[rt][1] + bias.y;
                r.z = acc[rt][2] + bias.z;
                r.w = acc[rt][3] + bias.w;
                if (ct == 0) {
                    __half* p = q2h + (size_t)row * 16 + c0;  // padded row: cols>=10 are 0
                    *(__half2*)p = __floats2half2_rn(r.x, r.y);
                    *(__half2*)(p + 2) = __floats2half2_rn(r.z, r.w);
                } else if (ct == 1) {
                    __half* p = kv2h + (size_t)row * 32 + c0;
                    *(__half2*)p = __floats2half2_rn(r.x, r.y);
                    *(__half2*)(p + 2) = __floats2half2_rn(r.z, r.w);
                } else if (ct == 2) {
                    __half* p = kv2h + (size_t)row * 32 + 16 + c0;
                    *(__half2*)p = __floats2half2_rn(r.x, r.y);
                    *(__half2*)(p + 2) = __floats2half2_rn(r.z, r.w);
                } else {
                    // s2 -> out f32 [N][10]; only cols 0..9 exist
                    if (g < 2) {
                        *(float4*)(out + (size_t)row * 10 + c0) = r;
                    } else if (g == 2) {
                        out[(size_t)row * 10 + 8] = r.x;
                        out[(size_t)row * 10 + 9] = r.y;
                    }
                }
            }
        }
    }
}

// ---------- layer-2 fused attention: packed 64B/node kv, static-shift softmax ----------
__global__ __launch_bounds__(256) void node_attn2(
    const __half* __restrict__ q2h, const __half* __restrict__ kv2h,
    const int* __restrict__ rowptr, const int* __restrict__ esrc,
    float* __restrict__ out)  // pre-loaded with skip (h @ Ws2 + bs2)
{
    const int t = threadIdx.x;
    const int d = blockIdx.x * 16 + (t >> 4);
    if (d >= NN) return;
    const int c = t & 15;
    const bool act = c < 10;
    const int beg = rowptr[d];
    const int end = rowptr[d + 1];
    const float qv = act ? (float)q2h[(size_t)d * 16 + c] * 0.31622776601683794f : 0.f;

    float accA = 0.f, sA = 0.f;
    float accB = 0.f, sB = 0.f;

    int i = beg;
    int sa = (i < end) ? esrc[i] : 0;
    int sb = (i + 1 < end) ? esrc[i + 1] : 0;
    float kA = (float)kv2h[(size_t)sa * 32 + c];
    float vA = (float)kv2h[(size_t)sa * 32 + 16 + c];
    float kB = (float)kv2h[(size_t)sb * 32 + c];
    float vB = (float)kv2h[(size_t)sb * 32 + 16 + c];

    while (i + 1 < end) {
        const int ni = i + 2;
        const int nsa = (ni < end) ? esrc[ni] : 0;
        const int nsb = (ni + 1 < end) ? esrc[ni + 1] : 0;
        const float nkA = (float)kv2h[(size_t)nsa * 32 + c];
        const float nvA = (float)kv2h[(size_t)nsa * 32 + 16 + c];
        const float nkB = (float)kv2h[(size_t)nsb * 32 + c];
        const float nvB = (float)kv2h[(size_t)nsb * 32 + 16 + c];

        float pA = qv * kA;
        float pB = qv * kB;
        pA += __shfl_xor(pA, 8, 16); pB += __shfl_xor(pB, 8, 16);
        pA += __shfl_xor(pA, 4, 16); pB += __shfl_xor(pB, 4, 16);
        pA += __shfl_xor(pA, 2, 16); pB += __shfl_xor(pB, 2, 16);
        pA += __shfl_xor(pA, 1, 16); pB += __shfl_xor(pB, 1, 16);

        const float exA = __expf(pA - 2.0f);
        accA += exA * vA;
        sA += exA;

        const float exB = __expf(pB - 2.0f);
        accB += exB * vB;
        sB += exB;

        kA = nkA; vA = nvA; kB = nkB; vB = nvB;
        i = ni;
    }
    if (i < end) {
        float pA = qv * kA;
        pA += __shfl_xor(pA, 8, 16);
        pA += __shfl_xor(pA, 4, 16);
        pA += __shfl_xor(pA, 2, 16);
        pA += __shfl_xor(pA, 1, 16);
        const float exA = __expf(pA - 2.0f);
        accA += exA * vA;
        sA += exA;
    }

    if (act) {
        const float inv = 1.f / (sA + sB + 1e-16f);
        out[(size_t)d * 10 + c] += (accA + accB) * inv;
    }
}

extern "C" void kernel_launch(void* const* d_in, const int* in_sizes, int n_in,
                              void* d_out, int out_size, void* d_ws, size_t ws_size,
                              hipStream_t stream) {
    const float* x   = (const float*)d_in[0];
    const int*   ei  = (const int*)d_in[1];
    const float* Wq1 = (const float*)d_in[2];  const float* bq1 = (const float*)d_in[3];
    const float* Wk1 = (const float*)d_in[4];  const float* bk1 = (const float*)d_in[5];
    const float* Wv1 = (const float*)d_in[6];  const float* bv1 = (const float*)d_in[7];
    const float* Ws1 = (const float*)d_in[8];  const float* bs1 = (const float*)d_in[9];
    const float* Wq2 = (const float*)d_in[10]; const float* bq2 = (const float*)d_in[11];
    const float* Wk2 = (const float*)d_in[12]; const float* bk2 = (const float*)d_in[13];
    const float* Wv2 = (const float*)d_in[14]; const float* bv2 = (const float*)d_in[15];
    const float* Ws2 = (const float*)d_in[16]; const float* bs2 = (const float*)d_in[17];
    float* out = (float*)d_out;

    const int* src = ei;
    const int* dst = ei + EE;

    // workspace carve
    __half* q1h   = (__half*)d_ws;                      // N*128 f16
    __half* k1h   = q1h + (size_t)NN * 128;             // N*128 f16
    __half* v1h   = k1h + (size_t)NN * 128;             // N*128 f16
    __half* skiph = v1h + (size_t)NN * 128;             // N*128 f16 (x @ Ws + bs)
    __half* hb    = skiph + (size_t)NN * 128;           // N*128 f16 (h)
    __half* Wt    = hb + (size_t)NN * 128;              // 4*128*128 f16
    __half* W2t   = Wt + 4 * 128 * 128;                 // 64*128 f16
    __half* q2h   = W2t + 64 * 128;                     // N*16 f16 (padded)
    __half* kv2h  = q2h + (size_t)NN * 16;              // N*32 f16 (k|v packed, 64B/node)
    float* bias2  = (float*)(kv2h + (size_t)NN * 32);   // 64 f32
    int* deg      = (int*)(bias2 + 64);                 // N
    int* rowptr   = deg + NN;                           // N+1
    int* cursor   = rowptr + NN + 1;                    // N
    int* bsum     = cursor + NN;                        // NB
    int* esrc     = bsum + NB;                          // E (src sorted by dst)

    // CSR build (reused by both layers)
    hipMemsetAsync(deg, 0, (size_t)NN * sizeof(int), stream);
    deg_count<<<EE / 256, 256, 0, stream>>>(dst, deg);
    build_weights<<<64, 256, 0, stream>>>(Wq1, Wk1, Wv1, Ws1,
                                          Wq2, bq2, Wk2, bk2, Wv2, bv2, Ws2, bs2,
                                          Wt, W2t, bias2);
    block_sums<<<NB, 256, 0, stream>>>(deg, bsum);
    scan_bsums<<<1, 256, 0, stream>>>(bsum);
    write_rowptr<<<NB, 256, 0, stream>>>(deg, bsum, rowptr, cursor);
    scatter_edges<<<EE / 256, 256, 0, stream>>>(src, dst, cursor, esrc);

    // layer 1 projections via MFMA: reads x f32 directly, all-f16 outputs
    gemm_l1_mfma<<<dim3((NN + 127) / 128, 2), 128, 0, stream>>>(
        x, Wt, bq1, bk1, bv1, bs1, q1h, k1h, v1h, skiph);

    // fused layer-1 attention + skip + ELU -> h fp16
    node_attn1<<<NN / 4, 256, 0, stream>>>(q1h, k1h, v1h, rowptr, esrc, skiph, hb);

    // layer-2 projections via MFMA (s2 written directly to d_out)
    node_l2_mfma<<<(NN + 127) / 128, 128, 0, stream>>>(hb, W2t, bias2, q2h, kv2h, out);

    // fused layer-2 attention (packed kv)
    node_attn2<<<NN / 16, 256, 0, stream>>>(q2h, kv2h, rowptr, esrc, out);
}

// Round 13
// 219.839 us; speedup vs baseline: 1.0935x; 1.0935x over previous
//
#include <hip/hip_runtime.h>
#include <hip/hip_fp16.h>
#include <math.h>

#define NN 50000
#define EE 800000
#define NB 196  // ceil(NN/256)
// IN_DIM = 128, HEADS*HIDDEN = 128, NUM_CLASSES = 10

typedef _Float16 f16x8 __attribute__((ext_vector_type(8)));
typedef float f32x4 __attribute__((ext_vector_type(4)));

__device__ inline float elu1(float x) { return x > 0.f ? x : expm1f(x); }

// ---------- prep: W1 transpose (f16) + W2 pack (f16, zero-padded) in one kernel ----------
__global__ __launch_bounds__(256) void build_weights(
    const float* __restrict__ Wq, const float* __restrict__ Wk,
    const float* __restrict__ Wv, const float* __restrict__ Ws,
    const float* __restrict__ Wq2, const float* __restrict__ bq2,
    const float* __restrict__ Wk2, const float* __restrict__ bk2,
    const float* __restrict__ Wv2, const float* __restrict__ bv2,
    const float* __restrict__ Ws2, const float* __restrict__ bs2,
    __half* __restrict__ Wt, __half* __restrict__ W2t, float* __restrict__ bias2)
{
    // part A (blocks 0..31): W2[128][10] x4 -> W2t[64][128] zero-padded + bias2[64]
    const int idx = blockIdx.x * 256 + threadIdx.x;
    if (idx < 8192) {
        const int col = idx >> 7, k = idx & 127;
        const int m = col >> 4, j = col & 15;
        const float* W = m == 0 ? Wq2 : m == 1 ? Wk2 : m == 2 ? Wv2 : Ws2;
        W2t[idx] = (__half)(j < 10 ? W[k * 10 + j] : 0.f);
    }
    if (idx < 64) {
        const int m = idx >> 4, j = idx & 15;
        const float* b = m == 0 ? bq2 : m == 1 ? bk2 : m == 2 ? bv2 : bs2;
        bias2[idx] = j < 10 ? b[j] : 0.f;
    }
    // part B (all 64 blocks): W1[k][c] -> Wt[mat][c][k] f16 via LDS tile transpose
    __shared__ float tile[32][33];
    const int mat = blockIdx.x >> 4;
    const int tid = blockIdx.x & 15;
    const int k0 = (tid >> 2) * 32, c0 = (tid & 3) * 32;
    const float* W = mat == 0 ? Wq : mat == 1 ? Wk : mat == 2 ? Wv : Ws;
    const int r = threadIdx.x >> 5;   // 0..7
    const int c = threadIdx.x & 31;
    for (int rr = r; rr < 32; rr += 8) tile[rr][c] = W[(size_t)(k0 + rr) * 128 + c0 + c];
    __syncthreads();
    for (int rr = r; rr < 32; rr += 8)
        Wt[((size_t)mat * 128 + c0 + rr) * 128 + k0 + c] = (__half)tile[c][rr];
}

// ---------- CSR build: multi-block scan, scatter (histogram fused into gemm) ----------
__global__ __launch_bounds__(256) void block_sums(
    const int* __restrict__ deg, int* __restrict__ bsum)
{
    __shared__ int ws[4];
    const int t = threadIdx.x;
    const int idx = blockIdx.x * 256 + t;
    int d = (idx < NN) ? deg[idx] : 0;
    #pragma unroll
    for (int off = 32; off; off >>= 1) d += __shfl_down(d, off, 64);
    if ((t & 63) == 0) ws[t >> 6] = d;
    __syncthreads();
    if (t == 0) bsum[blockIdx.x] = ws[0] + ws[1] + ws[2] + ws[3];
}

__global__ __launch_bounds__(256) void scan_bsums(int* __restrict__ bsum)
{
    __shared__ int s[256];
    const int t = threadIdx.x;
    int v = (t < NB) ? bsum[t] : 0;
    s[t] = v;
    __syncthreads();
    for (int off = 1; off < 256; off <<= 1) {
        int u = (t >= off) ? s[t - off] : 0;
        __syncthreads();
        s[t] += u;
        __syncthreads();
    }
    if (t < NB) bsum[t] = (t == 0) ? 0 : s[t - 1];
}

__global__ __launch_bounds__(256) void write_rowptr(
    const int* __restrict__ deg, const int* __restrict__ bsum,
    int* __restrict__ rowptr, int* __restrict__ cursor)
{
    __shared__ int s[256];
    const int t = threadIdx.x;
    const int idx = blockIdx.x * 256 + t;
    const int d = (idx < NN) ? deg[idx] : 0;
    s[t] = d;
    __syncthreads();
    for (int off = 1; off < 256; off <<= 1) {
        int u = (t >= off) ? s[t - off] : 0;
        __syncthreads();
        s[t] += u;
        __syncthreads();
    }
    const int excl = ((t == 0) ? 0 : s[t - 1]) + bsum[blockIdx.x];
    if (idx < NN) {
        rowptr[idx] = excl;
        cursor[idx] = excl;
    }
    if (idx == NN - 1) rowptr[NN] = excl + d;  // == EE
}

__global__ __launch_bounds__(256) void scatter_edges(
    const int* __restrict__ src, const int* __restrict__ dst,
    int* __restrict__ cursor, int* __restrict__ esrc)
{
    const int e = blockIdx.x * 256 + threadIdx.x;
    if (e >= EE) return;
    const int d = dst[e];
    const int pos = atomicAdd(&cursor[d], 1);
    esrc[pos] = src[e];
}

// ---------- layer-1 projections via MFMA: 2 matrices per block (blockIdx.y) ----------
// Reads x f32 directly; all-f16 outputs. Dst-degree histogram FUSED (coalesced
// 8-edges/thread sweep hides under MFMA + stores; kills the deg_count launch).
__global__ __launch_bounds__(128) void gemm_l1_mfma(
    const float* __restrict__ x, const __half* __restrict__ Wt,
    const float* __restrict__ bq, const float* __restrict__ bk,
    const float* __restrict__ bv, const float* __restrict__ bs,
    const int* __restrict__ dst, int* __restrict__ deg,
    __half* __restrict__ oqh, __half* __restrict__ okh,
    __half* __restrict__ ovh, __half* __restrict__ osh)
{
    const int pair = blockIdx.y;  // 0: mats {0,1}; 1: mats {2,3}
    const int t = threadIdx.x;

    // fused degree histogram: 100096 threads x 8 edges, coalesced
    {
        const int gtid = (blockIdx.y * gridDim.x + blockIdx.x) * 128 + t;
        #pragma unroll
        for (int u = 0; u < 8; ++u) {
            const int e = u * 100096 + gtid;
            if (e < EE) atomicAdd(&deg[dst[e]], 1);
        }
    }

    const int wave = t >> 6;
    const int lane = t & 63;
    const int l = lane & 15;
    const int g = lane >> 4;  // 0..3
    const int wrow0 = blockIdx.x * 128 + wave * 64;
    if (wrow0 >= NN) return;
    const bool full = (wrow0 + 64 <= NN);

    // x fragments (B operand): f32 load + in-register cvt; lane&15 = row-in-tile
    f16x8 xf[4][4];
    #pragma unroll
    for (int rt = 0; rt < 4; ++rt) {
        int arow = wrow0 + rt * 16 + l;
        if (!full && arow >= NN) arow = NN - 1;  // clamp: garbage rows never stored
        #pragma unroll
        for (int kk = 0; kk < 4; ++kk) {
            const float* xp = x + (size_t)arow * 128 + kk * 32 + g * 8;
            const float4 a = *(const float4*)xp;
            const float4 b = *(const float4*)(xp + 4);
            f16x8 f;
            f[0] = (_Float16)a.x; f[1] = (_Float16)a.y;
            f[2] = (_Float16)a.z; f[3] = (_Float16)a.w;
            f[4] = (_Float16)b.x; f[5] = (_Float16)b.y;
            f[6] = (_Float16)b.z; f[7] = (_Float16)b.w;
            xf[rt][kk] = f;
        }
    }

    for (int mi = 0; mi < 2; ++mi) {
        const int mat = pair * 2 + mi;
        const float* b = mat == 0 ? bq : mat == 1 ? bk : mat == 2 ? bv : bs;
        const _Float16* wt = (const _Float16*)Wt + (size_t)mat * 128 * 128;

        f16x8 wf[4], wfn[4];
        #pragma unroll
        for (int kk = 0; kk < 4; ++kk)
            wf[kk] = *(const f16x8*)(wt + (size_t)l * 128 + kk * 32 + g * 8);

        for (int ct = 0; ct < 8; ++ct) {
            if (ct < 7) {
                const int ncol = (ct + 1) * 16 + l;
                #pragma unroll
                for (int kk = 0; kk < 4; ++kk)
                    wfn[kk] = *(const f16x8*)(wt + (size_t)ncol * 128 + kk * 32 + g * 8);
            }
            f32x4 acc[4];
            #pragma unroll
            for (int rt = 0; rt < 4; ++rt) acc[rt] = (f32x4){0.f, 0.f, 0.f, 0.f};
            #pragma unroll
            for (int kk = 0; kk < 4; ++kk)
                #pragma unroll
                for (int rt = 0; rt < 4; ++rt)
                    acc[rt] = __builtin_amdgcn_mfma_f32_16x16x32_f16(wf[kk], xf[rt][kk], acc[rt], 0, 0, 0);

            const int col0 = ct * 16 + g * 4;
            const float4 bias = *(const float4*)(b + col0);
            __half* o = mat == 0 ? oqh : mat == 1 ? okh : mat == 2 ? ovh : osh;
            #pragma unroll
            for (int rt = 0; rt < 4; ++rt) {
                const int row = wrow0 + rt * 16 + l;
                if (full || row < NN) {
                    __half* p = o + (size_t)row * 128 + col0;
                    *(__half2*)p = __floats2half2_rn(acc[rt][0] + bias.x, acc[rt][1] + bias.y);
                    *(__half2*)(p + 2) = __floats2half2_rn(acc[rt][2] + bias.z, acc[rt][3] + bias.w);
                }
            }
            #pragma unroll
            for (int kk = 0; kk < 4; ++kk) wf[kk] = wfn[kk];
        }
    }
}

// ---------- layer-1 fused attention + skip + ELU -> h (fp16) ----------
// static-shift softmax (shift-invariant; logits ~ N(0,1) so exp(lg-4) is safe).
__global__ __launch_bounds__(256) void node_attn1(
    const __half* __restrict__ q1, const __half* __restrict__ k1,
    const __half* __restrict__ v1,
    const int* __restrict__ rowptr, const int* __restrict__ esrc,
    const __half* __restrict__ skiph,  // x @ Ws + bs (f16)
    __half* __restrict__ hb)           // out: h = elu(skip + attn), fp16
{
    const int t = threadIdx.x;
    const int wid = __builtin_amdgcn_readfirstlane(t >> 6);
    const int d = blockIdx.x * 4 + wid;
    if (d >= NN) return;
    const int lane = t & 63;
    const int ch2 = lane << 1;

    const int beg = rowptr[d];
    const int end = rowptr[d + 1];

    float2 qv = __half22float2(*(const __half2*)(q1 + (size_t)d * 128 + ch2));
    qv.x *= 0.17677669529663687f;  // fold 1/sqrt(32) into q
    qv.y *= 0.17677669529663687f;

    float2 accA = make_float2(0.f, 0.f), accB = make_float2(0.f, 0.f);
    float sA = 0.f, sB = 0.f;

    int i = beg;
    int sa = (i < end) ? esrc[i] : 0;
    int sb = (i + 1 < end) ? esrc[i + 1] : 0;
    __half2 kA = *(const __half2*)(k1 + (size_t)sa * 128 + ch2);
    __half2 vA = *(const __half2*)(v1 + (size_t)sa * 128 + ch2);
    __half2 kB = *(const __half2*)(k1 + (size_t)sb * 128 + ch2);
    __half2 vB = *(const __half2*)(v1 + (size_t)sb * 128 + ch2);

    while (i + 1 < end) {
        const int ni = i + 2;
        const int nsa = (ni < end) ? esrc[ni] : 0;
        const int nsb = (ni + 1 < end) ? esrc[ni + 1] : 0;
        const __half2 nkA = *(const __half2*)(k1 + (size_t)nsa * 128 + ch2);
        const __half2 nvA = *(const __half2*)(v1 + (size_t)nsa * 128 + ch2);
        const __half2 nkB = *(const __half2*)(k1 + (size_t)nsb * 128 + ch2);
        const __half2 nvB = *(const __half2*)(v1 + (size_t)nsb * 128 + ch2);

        const float2 kAf = __half22float2(kA);
        const float2 kBf = __half22float2(kB);
        const float2 vAf = __half22float2(vA);
        const float2 vBf = __half22float2(vB);

        float pA = qv.x * kAf.x + qv.y * kAf.y;
        float pB = qv.x * kBf.x + qv.y * kBf.y;
        pA += __shfl_xor(pA, 8, 16); pB += __shfl_xor(pB, 8, 16);
        pA += __shfl_xor(pA, 4, 16); pB += __shfl_xor(pB, 4, 16);
        pA += __shfl_xor(pA, 2, 16); pB += __shfl_xor(pB, 2, 16);
        pA += __shfl_xor(pA, 1, 16); pB += __shfl_xor(pB, 1, 16);

        const float exA = __expf(pA - 4.0f);
        accA.x += exA * vAf.x;
        accA.y += exA * vAf.y;
        sA += exA;

        const float exB = __expf(pB - 4.0f);
        accB.x += exB * vBf.x;
        accB.y += exB * vBf.y;
        sB += exB;

        kA = nkA; vA = nvA; kB = nkB; vB = nvB;
        i = ni;
    }
    if (i < end) {  // odd tail -> chain A
        const float2 kAf = __half22float2(kA);
        const float2 vAf = __half22float2(vA);
        float pA = qv.x * kAf.x + qv.y * kAf.y;
        pA += __shfl_xor(pA, 8, 16);
        pA += __shfl_xor(pA, 4, 16);
        pA += __shfl_xor(pA, 2, 16);
        pA += __shfl_xor(pA, 1, 16);
        const float exA = __expf(pA - 4.0f);
        accA.x += exA * vAf.x;
        accA.y += exA * vAf.y;
        sA += exA;
    }

    const float inv = 1.f / (sA + sB + 1e-16f);
    float2 o = __half22float2(*(const __half2*)(skiph + (size_t)d * 128 + ch2));
    o.x = elu1(o.x + (accA.x + accB.x) * inv);
    o.y = elu1(o.y + (accA.y + accB.y) * inv);
    *(__half2*)(hb + (size_t)d * 128 + ch2) = __floats2half2_rn(o.x, o.y);
}

// ---------- layer-2 projections via MFMA: h[N,128] @ W2t^T + bias2 ----------
// ct tile = matrix: 0->q2h[N][16], 1->k half of kv2h, 2->v half, 3->s2 (f32 out).
__global__ __launch_bounds__(128) void node_l2_mfma(
    const __half* __restrict__ hb, const __half* __restrict__ W2t,
    const float* __restrict__ bias2,
    __half* __restrict__ q2h, __half* __restrict__ kv2h,
    float* __restrict__ out)
{
    const int t = threadIdx.x;
    const int wave = t >> 6;
    const int lane = t & 63;
    const int l = lane & 15;
    const int g = lane >> 4;  // 0..3
    const int wrow0 = blockIdx.x * 128 + wave * 64;
    if (wrow0 >= NN) return;
    const bool full = (wrow0 + 64 <= NN);

    f16x8 hf[4][4];
    #pragma unroll
    for (int rt = 0; rt < 4; ++rt) {
        int arow = wrow0 + rt * 16 + l;
        if (!full && arow >= NN) arow = NN - 1;
        #pragma unroll
        for (int kk = 0; kk < 4; ++kk)
            hf[rt][kk] = *(const f16x8*)((const _Float16*)hb + (size_t)arow * 128 + kk * 32 + g * 8);
    }

    #pragma unroll
    for (int ct = 0; ct < 4; ++ct) {
        const int col = ct * 16 + l;
        f16x8 wf[4];
        #pragma unroll
        for (int kk = 0; kk < 4; ++kk)
            wf[kk] = *(const f16x8*)((const _Float16*)W2t + (size_t)col * 128 + kk * 32 + g * 8);

        f32x4 acc[4];
        #pragma unroll
        for (int rt = 0; rt < 4; ++rt) acc[rt] = (f32x4){0.f, 0.f, 0.f, 0.f};
        #pragma unroll
        for (int kk = 0; kk < 4; ++kk)
            #pragma unroll
            for (int rt = 0; rt < 4; ++rt)
                acc[rt] = __builtin_amdgcn_mfma_f32_16x16x32_f16(wf[kk], hf[rt][kk], acc[rt], 0, 0, 0);

        const int c0 = g * 4;  // within-tile column base
        const float4 bias = *(const float4*)(bias2 + ct * 16 + c0);
        #pragma unroll
        for (int rt = 0; rt < 4; ++rt) {
            const int row = wrow0 + rt * 16 + l;
            if (full || row < NN) {
                float4 r;
                r.x = acc[rt][0] + bias.x;
                r.y = acc[rt][1] + bias.y;
                r.z = acc[rt][2] + bias.z;
                r.w = acc[rt][3] + bias.w;
                if (ct == 0) {
                    __half* p = q2h + (size_t)row * 16 + c0;  // padded row: cols>=10 are 0
                    *(__half2*)p = __floats2half2_rn(r.x, r.y);
                    *(__half2*)(p + 2) = __floats2half2_rn(r.z, r.w);
                } else if (ct == 1) {
                    __half* p = kv2h + (size_t)row * 32 + c0;
                    *(__half2*)p = __floats2half2_rn(r.x, r.y);
                    *(__half2*)(p + 2) = __floats2half2_rn(r.z, r.w);
                } else if (ct == 2) {
                    __half* p = kv2h + (size_t)row * 32 + 16 + c0;
                    *(__half2*)p = __floats2half2_rn(r.x, r.y);
                    *(__half2*)(p + 2) = __floats2half2_rn(r.z, r.w);
                } else {
                    // s2 -> out f32 [N][10]; only cols 0..9 exist
                    if (g < 2) {
                        *(float4*)(out + (size_t)row * 10 + c0) = r;
                    } else if (g == 2) {
                        out[(size_t)row * 10 + 8] = r.x;
                        out[(size_t)row * 10 + 9] = r.y;
                    }
                }
            }
        }
    }
}

// ---------- layer-2 fused attention: 8 lanes/dst, half2 loads, zero predication ----
// q2h/kv2h channels 10..15 are exact zeros -> 8-lane shfl dot is exact; pad lanes
// accumulate zeros. 32 dsts per 256-thread block; per-edge loads halved.
__global__ __launch_bounds__(256) void node_attn2(
    const __half* __restrict__ q2h, const __half* __restrict__ kv2h,
    const int* __restrict__ rowptr, const int* __restrict__ esrc,
    float* __restrict__ out)  // pre-loaded with skip (h @ Ws2 + bs2)
{
    const int t = threadIdx.x;
    const int d = blockIdx.x * 32 + (t >> 3);
    if (d >= NN) return;
    const int c = t & 7;  // channel pair (2c, 2c+1)
    const int beg = rowptr[d];
    const int end = rowptr[d + 1];

    float2 qv = __half22float2(*(const __half2*)(q2h + (size_t)d * 16 + 2 * c));
    qv.x *= 0.31622776601683794f;  // fold 1/sqrt(10)
    qv.y *= 0.31622776601683794f;

    float2 accA = make_float2(0.f, 0.f), accB = make_float2(0.f, 0.f);
    float sA = 0.f, sB = 0.f;

    int i = beg;
    int sa = (i < end) ? esrc[i] : 0;
    int sb = (i + 1 < end) ? esrc[i + 1] : 0;
    __half2 kA = *(const __half2*)(kv2h + (size_t)sa * 32 + 2 * c);
    __half2 vA = *(const __half2*)(kv2h + (size_t)sa * 32 + 16 + 2 * c);
    __half2 kB = *(const __half2*)(kv2h + (size_t)sb * 32 + 2 * c);
    __half2 vB = *(const __half2*)(kv2h + (size_t)sb * 32 + 16 + 2 * c);

    while (i + 1 < end) {
        const int ni = i + 2;
        const int nsa = (ni < end) ? esrc[ni] : 0;
        const int nsb = (ni + 1 < end) ? esrc[ni + 1] : 0;
        const __half2 nkA = *(const __half2*)(kv2h + (size_t)nsa * 32 + 2 * c);
        const __half2 nvA = *(const __half2*)(kv2h + (size_t)nsa * 32 + 16 + 2 * c);
        const __half2 nkB = *(const __half2*)(kv2h + (size_t)nsb * 32 + 2 * c);
        const __half2 nvB = *(const __half2*)(kv2h + (size_t)nsb * 32 + 16 + 2 * c);

        const float2 kAf = __half22float2(kA);
        const float2 kBf = __half22float2(kB);
        const float2 vAf = __half22float2(vA);
        const float2 vBf = __half22float2(vB);

        float pA = qv.x * kAf.x + qv.y * kAf.y;
        float pB = qv.x * kBf.x + qv.y * kBf.y;
        pA += __shfl_xor(pA, 4, 8); pB += __shfl_xor(pB, 4, 8);
        pA += __shfl_xor(pA, 2, 8); pB += __shfl_xor(pB, 2, 8);
        pA += __shfl_xor(pA, 1, 8); pB += __shfl_xor(pB, 1, 8);

        const float exA = __expf(pA - 2.0f);
        accA.x += exA * vAf.x;
        accA.y += exA * vAf.y;
        sA += exA;

        const float exB = __expf(pB - 2.0f);
        accB.x += exB * vBf.x;
        accB.y += exB * vBf.y;
        sB += exB;

        kA = nkA; vA = nvA; kB = nkB; vB = nvB;
        i = ni;
    }
    if (i < end) {
        const float2 kAf = __half22float2(kA);
        const float2 vAf = __half22float2(vA);
        float pA = qv.x * kAf.x + qv.y * kAf.y;
        pA += __shfl_xor(pA, 4, 8);
        pA += __shfl_xor(pA, 2, 8);
        pA += __shfl_xor(pA, 1, 8);
        const float exA = __expf(pA - 2.0f);
        accA.x += exA * vAf.x;
        accA.y += exA * vAf.y;
        sA += exA;
    }

    if (c < 5) {  // channels 2c, 2c+1 in 0..9
        const float inv = 1.f / (sA + sB + 1e-16f);
        float2 o = *(float2*)(out + (size_t)d * 10 + 2 * c);
        o.x += (accA.x + accB.x) * inv;
        o.y += (accA.y + accB.y) * inv;
        *(float2*)(out + (size_t)d * 10 + 2 * c) = o;
    }
}

extern "C" void kernel_launch(void* const* d_in, const int* in_sizes, int n_in,
                              void* d_out, int out_size, void* d_ws, size_t ws_size,
                              hipStream_t stream) {
    const float* x   = (const float*)d_in[0];
    const int*   ei  = (const int*)d_in[1];
    const float* Wq1 = (const float*)d_in[2];  const float* bq1 = (const float*)d_in[3];
    const float* Wk1 = (const float*)d_in[4];  const float* bk1 = (const float*)d_in[5];
    const float* Wv1 = (const float*)d_in[6];  const float* bv1 = (const float*)d_in[7];
    const float* Ws1 = (const float*)d_in[8];  const float* bs1 = (const float*)d_in[9];
    const float* Wq2 = (const float*)d_in[10]; const float* bq2 = (const float*)d_in[11];
    const float* Wk2 = (const float*)d_in[12]; const float* bk2 = (const float*)d_in[13];
    const float* Wv2 = (const float*)d_in[14]; const float* bv2 = (const float*)d_in[15];
    const float* Ws2 = (const float*)d_in[16]; const float* bs2 = (const float*)d_in[17];
    float* out = (float*)d_out;

    const int* src = ei;
    const int* dst = ei + EE;

    // workspace carve
    __half* q1h   = (__half*)d_ws;                      // N*128 f16
    __half* k1h   = q1h + (size_t)NN * 128;             // N*128 f16
    __half* v1h   = k1h + (size_t)NN * 128;             // N*128 f16
    __half* skiph = v1h + (size_t)NN * 128;             // N*128 f16 (x @ Ws + bs)
    __half* hb    = skiph + (size_t)NN * 128;           // N*128 f16 (h)
    __half* Wt    = hb + (size_t)NN * 128;              // 4*128*128 f16
    __half* W2t   = Wt + 4 * 128 * 128;                 // 64*128 f16
    __half* q2h   = W2t + 64 * 128;                     // N*16 f16 (padded)
    __half* kv2h  = q2h + (size_t)NN * 16;              // N*32 f16 (k|v packed, 64B/node)
    float* bias2  = (float*)(kv2h + (size_t)NN * 32);   // 64 f32
    int* deg      = (int*)(bias2 + 64);                 // N
    int* rowptr   = deg + NN;                           // N+1
    int* cursor   = rowptr + NN + 1;                    // N
    int* bsum     = cursor + NN;                        // NB
    int* esrc     = bsum + NB;                          // E (src sorted by dst)

    // prep
    hipMemsetAsync(deg, 0, (size_t)NN * sizeof(int), stream);
    build_weights<<<64, 256, 0, stream>>>(Wq1, Wk1, Wv1, Ws1,
                                          Wq2, bq2, Wk2, bk2, Wv2, bv2, Ws2, bs2,
                                          Wt, W2t, bias2);

    // layer 1 projections via MFMA (+ fused degree histogram)
    gemm_l1_mfma<<<dim3((NN + 127) / 128, 2), 128, 0, stream>>>(
        x, Wt, bq1, bk1, bv1, bs1, dst, deg, q1h, k1h, v1h, skiph);

    // CSR build (reused by both layers)
    block_sums<<<NB, 256, 0, stream>>>(deg, bsum);
    scan_bsums<<<1, 256, 0, stream>>>(bsum);
    write_rowptr<<<NB, 256, 0, stream>>>(deg, bsum, rowptr, cursor);
    scatter_edges<<<EE / 256, 256, 0, stream>>>(src, dst, cursor, esrc);

    // fused layer-1 attention + skip + ELU -> h fp16
    node_attn1<<<NN / 4, 256, 0, stream>>>(q1h, k1h, v1h, rowptr, esrc, skiph, hb);

    // layer-2 projections via MFMA (s2 written directly to d_out)
    node_l2_mfma<<<(NN + 127) / 128, 128, 0, stream>>>(hb, W2t, bias2, q2h, kv2h, out);

    // fused layer-2 attention (8 lanes/dst, half2)
    node_attn2<<<(NN + 31) / 32, 256, 0, stream>>>(q2h, kv2h, rowptr, esrc, out);
}